// Round 3
// baseline (8068.241 us; speedup 1.0000x reference)
//
#include <hip/hip_runtime.h>
#include <hip/hip_bf16.h>
#include <hip/hip_cooperative_groups.h>

#define N_DIM 1024
#define R_DIM 6
#define B_DIM 64
#define T_DIM 400
#define NWAVES 256   // 64 blocks x 4 waves

typedef short bf16x8 __attribute__((ext_vector_type(8)));
typedef float f32x4 __attribute__((ext_vector_type(4)));

__device__ inline unsigned short f2bf(float f) {
    unsigned int u = __float_as_uint(f);
    unsigned int r = (u + 0x7fffu + ((u >> 16) & 1u)) >> 16;
    return (unsigned short)r;
}

// Build W in MFMA B-fragment layout, bf16.
// WF[g][s][lane][i] = W[16g + (lane&15)][32s + (lane>>4)*8 + i]
// Block 0 also zeroes the 256 wave flags (deterministic per launch).
__global__ void __launch_bounds__(64) build_wf(
    const float* __restrict__ lv,
    const float* __restrict__ rv,
    const float* __restrict__ noise,
    unsigned short* __restrict__ wf,
    unsigned* __restrict__ flags)
{
    int blk = blockIdx.x;
    int l = threadIdx.x;
    if (blk == 0) {
        // 64 threads x 4 flags = 256
        flags[l * 4 + 0] = 0u;
        flags[l * 4 + 1] = 0u;
        flags[l * 4 + 2] = 0u;
        flags[l * 4 + 3] = 0u;
    }
    int g = blk >> 5;
    int s = blk & 31;
    int j = g * 16 + (l & 15);
    int n0 = s * 32 + (l >> 4) * 8;
    unsigned short* dst = wf + ((size_t)blk * 64 + l) * 8;
    float rj[R_DIM];
#pragma unroll
    for (int k = 0; k < R_DIM; ++k) rj[k] = rv[k * N_DIM + j];
#pragma unroll
    for (int i = 0; i < 8; ++i) {
        int n = n0 + i;
        float acc = noise[j * N_DIM + n];
        float dot = 0.f;
#pragma unroll
        for (int k = 0; k < R_DIM; ++k) dot += rj[k] * lv[k * N_DIM + n];
        acc += dot * (1.0f / (float)N_DIM);
        dst[i] = f2bf(acc);
    }
}

// Wait until all 256 wave flags reach `target`. Each lane watches 4 flags
// with relaxed agent-scope loads (no RMW, no contention), wave-wide vote.
__device__ inline void wait_all(const unsigned* flags, unsigned target, int l) {
    const unsigned* p = flags + l * 4;
    for (;;) {
        unsigned v0 = __hip_atomic_load(p + 0, __ATOMIC_RELAXED, __HIP_MEMORY_SCOPE_AGENT);
        unsigned v1 = __hip_atomic_load(p + 1, __ATOMIC_RELAXED, __HIP_MEMORY_SCOPE_AGENT);
        unsigned v2 = __hip_atomic_load(p + 2, __ATOMIC_RELAXED, __HIP_MEMORY_SCOPE_AGENT);
        unsigned v3 = __hip_atomic_load(p + 3, __ATOMIC_RELAXED, __HIP_MEMORY_SCOPE_AGENT);
        unsigned a = v0 < v1 ? v0 : v1;
        unsigned b = v2 < v3 ? v2 : v3;
        unsigned m = a < b ? a : b;
        if (__all(m >= target)) break;
        __builtin_amdgcn_s_sleep(1);
    }
    __threadfence();   // acquire: published a-values now visible
}

// 64 blocks x 256 threads (cooperative, for co-residency only).
// 256 fully autonomous waves; wave (g,w) owns batch rows [16w,16w+16)
// x j-cols [16g,16g+16). No __syncthreads in the T-loop.
__global__ void __launch_bounds__(256, 1) rnn_recurrence(
    const float* __restrict__ hidden0,
    const float* __restrict__ input,        // [B][T][N]
    const unsigned short* __restrict__ wf,
    float* __restrict__ out_hidden,         // [T][B][N]
    unsigned short* __restrict__ abuf0,
    unsigned short* __restrict__ abuf1,
    unsigned* __restrict__ flags)
{
    const int g = blockIdx.x;
    const int w = threadIdx.x >> 6;
    const int l = threadIdx.x & 63;
    const int wid = g * 4 + w;
    const int jcol = g * 16 + (l & 15);
    const int brow0 = w * 16 + (l >> 4) * 4;

    // ---- W slice into registers: 32 x bf16x8 = 128 VGPR ----
    const bf16x8* bfrag_base = reinterpret_cast<const bf16x8*>(wf) + (size_t)g * 32 * 64 + l;
    bf16x8 wreg[32];
#pragma unroll
    for (int s = 0; s < 32; ++s) wreg[s] = bfrag_base[s * 64];

    // ---- init h-state & publish a0 ----
    float h0v = hidden0[jcol];
    float h[4];
#pragma unroll
    for (int i = 0; i < 4; ++i) h[i] = h0v;
    unsigned short a0 = f2bf(tanhf(h0v));
#pragma unroll
    for (int i = 0; i < 4; ++i) abuf0[(brow0 + i) * N_DIM + jcol] = a0;
    if (l == 0)
        __hip_atomic_store(&flags[wid], 1u, __ATOMIC_RELEASE, __HIP_MEMORY_SCOPE_AGENT);

    const int arow = w * 16 + (l & 15);
    const int aoff_us = arow * N_DIM + (l >> 4) * 8;

    // prefetch x for t=0
    float x[4];
#pragma unroll
    for (int i = 0; i < 4; ++i)
        x[i] = input[((size_t)(brow0 + i) * T_DIM + 0) * N_DIM + jcol];

    for (int t = 0; t < T_DIM; ++t) {
        wait_all(flags, (unsigned)(t + 1), l);

        const unsigned short* acur = (t & 1) ? abuf1 : abuf0;
        unsigned short* anext = (t & 1) ? abuf0 : abuf1;
        const bf16x8* afrag = reinterpret_cast<const bf16x8*>(acur + aoff_us);

        f32x4 acc0 = {0.f, 0.f, 0.f, 0.f};
        f32x4 acc1 = {0.f, 0.f, 0.f, 0.f};
        bf16x8 av[16];

#pragma unroll
        for (int s = 0; s < 16; ++s) av[s] = afrag[s * 4];

        // prefetch x_{t+1} while MFMAs run
        float xn[4];
        if (t + 1 < T_DIM) {
#pragma unroll
            for (int i = 0; i < 4; ++i)
                xn[i] = input[((size_t)(brow0 + i) * T_DIM + (t + 1)) * N_DIM + jcol];
        }

#pragma unroll
        for (int s = 0; s < 16; s += 2) {
            acc0 = __builtin_amdgcn_mfma_f32_16x16x32_bf16(av[s],     wreg[s],     acc0, 0, 0, 0);
            acc1 = __builtin_amdgcn_mfma_f32_16x16x32_bf16(av[s + 1], wreg[s + 1], acc1, 0, 0, 0);
        }
#pragma unroll
        for (int s = 0; s < 16; ++s) av[s] = afrag[(16 + s) * 4];
#pragma unroll
        for (int s = 0; s < 16; s += 2) {
            acc0 = __builtin_amdgcn_mfma_f32_16x16x32_bf16(av[s],     wreg[16 + s],     acc0, 0, 0, 0);
            acc1 = __builtin_amdgcn_mfma_f32_16x16x32_bf16(av[s + 1], wreg[16 + s + 1], acc1, 0, 0, 0);
        }
        f32x4 acc = acc0 + acc1;

        // ---- epilogue, critical-path ordered ----
        float a[4];
#pragma unroll
        for (int i = 0; i < 4; ++i) {
            float hn = 0.9f * h[i] + 0.1f * (acc[i] + x[i]);
            h[i] = hn;
            a[i] = tanhf(hn);
        }
        // 1) publish a_{t+1} (consumed by other waves)
#pragma unroll
        for (int i = 0; i < 4; ++i)
            anext[(brow0 + i) * N_DIM + jcol] = f2bf(a[i]);
        // 2) release flag (vmcnt drain covers the anext stores)
        if (l == 0)
            __hip_atomic_store(&flags[wid], (unsigned)(t + 2), __ATOMIC_RELEASE,
                               __HIP_MEMORY_SCOPE_AGENT);
        // 3) out_hidden stores — off the inter-wave critical path
#pragma unroll
        for (int i = 0; i < 4; ++i)
            out_hidden[((size_t)t * B_DIM + (brow0 + i)) * N_DIM + jcol] = a[i];
#pragma unroll
        for (int i = 0; i < 4; ++i) x[i] = xn[i];
    }
}

__global__ void __launch_bounds__(256) geo_kernel(
    const float* __restrict__ hid,
    const float* __restrict__ gW,
    const float* __restrict__ gb,
    const float* __restrict__ rW,
    float* __restrict__ geo,
    float* __restrict__ ro)
{
    int row = blockIdx.x * 4 + (threadIdx.x >> 6);
    int l = threadIdx.x & 63;
    const float* hrow = hid + (size_t)row * N_DIM;
    float a0 = 0.f, a1 = 0.f;
#pragma unroll
    for (int i = 0; i < N_DIM / 64; ++i) {
        int idx = i * 64 + l;
        float th = tanhf(hrow[idx]);
        a0 += th * gW[idx];
        a1 += th * gW[N_DIM + idx];
    }
#pragma unroll
    for (int off = 32; off; off >>= 1) {
        a0 += __shfl_down(a0, off);
        a1 += __shfl_down(a1, off);
    }
    if (l == 0) {
        float g0 = a0 + gb[0];
        float g1 = a1 + gb[1];
        geo[(size_t)row * 2 + 0] = g0;
        geo[(size_t)row * 2 + 1] = g1;
#pragma unroll
        for (int m = 0; m < 6; ++m)
            ro[(size_t)row * 6 + m] = g0 * rW[m * 2] + g1 * rW[m * 2 + 1];
    }
}

extern "C" void kernel_launch(void* const* d_in, const int* in_sizes, int n_in,
                              void* d_out, int out_size, void* d_ws, size_t ws_size,
                              hipStream_t stream) {
    const float* hidden0 = (const float*)d_in[0];
    const float* input   = (const float*)d_in[1];
    const float* lv      = (const float*)d_in[2];
    const float* rv      = (const float*)d_in[3];
    const float* noise   = (const float*)d_in[4];
    const float* gW      = (const float*)d_in[5];
    const float* gb      = (const float*)d_in[6];
    const float* rW      = (const float*)d_in[7];

    float* out_hidden = (float*)d_out;
    float* geo = out_hidden + (size_t)T_DIM * B_DIM * N_DIM;
    float* ro  = geo + (size_t)T_DIM * B_DIM * 2;

    unsigned short* wf    = (unsigned short*)d_ws;                  // 2 MB
    unsigned short* abuf0 = wf + (size_t)64 * 32 * 64 * 8;          // 128 KB
    unsigned short* abuf1 = abuf0 + (size_t)B_DIM * N_DIM;          // 128 KB
    unsigned* flags = (unsigned*)(abuf1 + (size_t)B_DIM * N_DIM);   // 1 KB

    build_wf<<<2048, 64, 0, stream>>>(lv, rv, noise, wf, flags);

    void* args[] = { (void*)&hidden0, (void*)&input, (void*)&wf,
                     (void*)&out_hidden, (void*)&abuf0, (void*)&abuf1, (void*)&flags };
    hipLaunchCooperativeKernel((const void*)rnn_recurrence, dim3(64), dim3(256),
                               args, 0, stream);

    geo_kernel<<<(T_DIM * B_DIM) / 4, 256, 0, stream>>>(out_hidden, gW, gb, rW, geo, ro);
}

// Round 4
// 3884.969 us; speedup vs baseline: 2.0768x; 2.0768x over previous
//
#include <hip/hip_runtime.h>
#include <hip/hip_bf16.h>

#define N_DIM 1024
#define R_DIM 6
#define B_DIM 64
#define T_DIM 400
#define FLAG_STRIDE 16   // one flag per 64B cacheline

typedef short bf16x8 __attribute__((ext_vector_type(8)));
typedef float f32x4 __attribute__((ext_vector_type(4)));

__device__ inline unsigned short f2bf(float f) {
    unsigned int u = __float_as_uint(f);
    unsigned int r = (u + 0x7fffu + ((u >> 16) & 1u)) >> 16;
    return (unsigned short)r;
}

// Build W in MFMA B-fragment layout, bf16.
// WF[g][s][lane][i] = W[16g + (lane&15)][32s + (lane>>4)*8 + i]
// Block 0 zeroes the 64 per-block flags (deterministic per launch).
__global__ void __launch_bounds__(64) build_wf(
    const float* __restrict__ lv,
    const float* __restrict__ rv,
    const float* __restrict__ noise,
    unsigned short* __restrict__ wf,
    unsigned* __restrict__ flags)
{
    int blk = blockIdx.x;
    int l = threadIdx.x;
    if (blk == 0) flags[l * FLAG_STRIDE] = 0u;
    int g = blk >> 5;
    int s = blk & 31;
    int j = g * 16 + (l & 15);
    int n0 = s * 32 + (l >> 4) * 8;
    unsigned short* dst = wf + ((size_t)blk * 64 + l) * 8;
    float rj[R_DIM];
#pragma unroll
    for (int k = 0; k < R_DIM; ++k) rj[k] = rv[k * N_DIM + j];
#pragma unroll
    for (int i = 0; i < 8; ++i) {
        int n = n0 + i;
        float acc = noise[j * N_DIM + n];
        float dot = 0.f;
#pragma unroll
        for (int k = 0; k < R_DIM; ++k) dot += rj[k] * lv[k * N_DIM + n];
        acc += dot * (1.0f / (float)N_DIM);
        dst[i] = f2bf(acc);
    }
}

// Publish a[4] (rows brow0..brow0+3, col jcol) as packed 2xbf16 u32
// relaxed agent-scope atomic stores (write through to Infinity Cache).
__device__ inline void publish_a(unsigned short* dst, const float a[4],
                                 int brow0, int jcol, int l) {
    unsigned* d32 = (unsigned*)dst;
    int j0 = jcol & ~1;
    int odd = l & 1;
#pragma unroll
    for (int i = 0; i < 4; ++i) {
        float other = __shfl_xor(a[i], 1);
        unsigned mine = f2bf(a[i]);
        unsigned oth  = f2bf(other);
        unsigned pk = odd ? (oth | (mine << 16)) : (mine | (oth << 16));
        // even lanes store rows 0,1; odd lanes store rows 2,3
        if ((odd == 0 && i < 2) || (odd == 1 && i >= 2)) {
            int b = brow0 + i;
            __hip_atomic_store(&d32[(b * N_DIM + j0) >> 1], pk,
                               __ATOMIC_RELAXED, __HIP_MEMORY_SCOPE_AGENT);
        }
    }
}

// Wave 0 only: lane l watches block l's flag.
__device__ inline void poll_flags(const unsigned* flags, unsigned target, int l) {
    for (;;) {
        unsigned v = __hip_atomic_load(&flags[l * FLAG_STRIDE],
                                       __ATOMIC_RELAXED, __HIP_MEMORY_SCOPE_AGENT);
        if (__all(v >= target)) break;
        __builtin_amdgcn_s_sleep(1);
    }
}

// 64 blocks x 256 threads (cooperative launch for co-residency only).
// Block g owns j-cols [16g,16g+16) for all 64 batches; wave w owns batch
// rows [16w,16w+16). No fences in the T-loop: all cross-block data moves
// via relaxed agent atomics; ordering via vmcnt(0) + raw s_barrier.
__global__ void __launch_bounds__(256, 1) rnn_recurrence(
    const float* __restrict__ hidden0,
    const float* __restrict__ input,        // [B][T][N]
    const unsigned short* __restrict__ wf,
    float* __restrict__ out_hidden,         // [T][B][N]
    unsigned short* __restrict__ abuf0,
    unsigned short* __restrict__ abuf1,
    unsigned* __restrict__ flags)
{
    const int g = blockIdx.x;
    const int tid = threadIdx.x;
    const int w = tid >> 6;
    const int l = tid & 63;
    const int jcol = g * 16 + (l & 15);
    const int brow0 = w * 16 + (l >> 4) * 4;

    // W fragments (compiler may keep in regs or re-load; L2 stays warm now)
    const bf16x8* bfrag_base = reinterpret_cast<const bf16x8*>(wf) + (size_t)g * 32 * 64 + l;
    bf16x8 wreg[32];
#pragma unroll
    for (int s = 0; s < 32; ++s) wreg[s] = bfrag_base[s * 64];

    // init h-state
    float h0v = hidden0[jcol];
    float h[4];
#pragma unroll
    for (int i = 0; i < 4; ++i) h[i] = h0v;

    // prefetch x for t=0 (normal cached loads)
    float x[4];
#pragma unroll
    for (int i = 0; i < 4; ++i)
        x[i] = input[((size_t)(brow0 + i) * T_DIM + 0) * N_DIM + jcol];

    // publish a0
    float a0[4];
#pragma unroll
    for (int i = 0; i < 4; ++i) a0[i] = tanhf(h0v);
    publish_a(abuf0, a0, brow0, jcol, l);
    asm volatile("s_waitcnt vmcnt(0)" ::: "memory");
    __builtin_amdgcn_s_barrier();
    if (tid == 0)
        __hip_atomic_store(&flags[g * FLAG_STRIDE], 1u,
                           __ATOMIC_RELAXED, __HIP_MEMORY_SCOPE_AGENT);
    if (w == 0) poll_flags(flags, 1u, l);
    __builtin_amdgcn_s_barrier();
    asm volatile("" ::: "memory");

    // u64 index of this lane's A-fragment base within the a-buffer
    const int aoff_u64 = ((w * 16 + (l & 15)) * N_DIM + (l >> 4) * 8) >> 2;

    for (int t = 0; t < T_DIM; ++t) {
        const unsigned short* acur = (t & 1) ? abuf1 : abuf0;
        unsigned short* anext = (t & 1) ? abuf0 : abuf1;
        const unsigned long long* ap = (const unsigned long long*)acur + aoff_u64;

        f32x4 acc0 = {0.f, 0.f, 0.f, 0.f};
        f32x4 acc1 = {0.f, 0.f, 0.f, 0.f};
        bf16x8 av[16];

        // stage first 16 fragments as relaxed atomic u64 pairs (from IF$)
#pragma unroll
        for (int s = 0; s < 16; ++s) {
            union { unsigned long long u[2]; bf16x8 v; } tmp;
            tmp.u[0] = __hip_atomic_load(ap + s * 8,     __ATOMIC_RELAXED, __HIP_MEMORY_SCOPE_AGENT);
            tmp.u[1] = __hip_atomic_load(ap + s * 8 + 1, __ATOMIC_RELAXED, __HIP_MEMORY_SCOPE_AGENT);
            av[s] = tmp.v;
        }

        // prefetch x_{t+1} while MFMAs run
        float xn[4];
        if (t + 1 < T_DIM) {
#pragma unroll
            for (int i = 0; i < 4; ++i)
                xn[i] = input[((size_t)(brow0 + i) * T_DIM + (t + 1)) * N_DIM + jcol];
        }

#pragma unroll
        for (int s = 0; s < 16; s += 2) {
            acc0 = __builtin_amdgcn_mfma_f32_16x16x32_bf16(av[s],     wreg[s],     acc0, 0, 0, 0);
            acc1 = __builtin_amdgcn_mfma_f32_16x16x32_bf16(av[s + 1], wreg[s + 1], acc1, 0, 0, 0);
        }
#pragma unroll
        for (int s = 0; s < 16; ++s) {
            union { unsigned long long u[2]; bf16x8 v; } tmp;
            tmp.u[0] = __hip_atomic_load(ap + (16 + s) * 8,     __ATOMIC_RELAXED, __HIP_MEMORY_SCOPE_AGENT);
            tmp.u[1] = __hip_atomic_load(ap + (16 + s) * 8 + 1, __ATOMIC_RELAXED, __HIP_MEMORY_SCOPE_AGENT);
            av[s] = tmp.v;
        }
#pragma unroll
        for (int s = 0; s < 16; s += 2) {
            acc0 = __builtin_amdgcn_mfma_f32_16x16x32_bf16(av[s],     wreg[16 + s],     acc0, 0, 0, 0);
            acc1 = __builtin_amdgcn_mfma_f32_16x16x32_bf16(av[s + 1], wreg[16 + s + 1], acc1, 0, 0, 0);
        }
        f32x4 acc = acc0 + acc1;

        // h update + activation
        float a[4];
#pragma unroll
        for (int i = 0; i < 4; ++i) {
            float hn = 0.9f * h[i] + 0.1f * (acc[i] + x[i]);
            h[i] = hn;
            a[i] = tanhf(hn);
        }
#pragma unroll
        for (int i = 0; i < 4; ++i) x[i] = xn[i];

        if (t + 1 < T_DIM) {
            publish_a(anext, a, brow0, jcol, l);
            asm volatile("s_waitcnt vmcnt(0)" ::: "memory");   // publishes at IF$
            __builtin_amdgcn_s_barrier();                      // all waves done
            if (tid == 0)
                __hip_atomic_store(&flags[g * FLAG_STRIDE], (unsigned)(t + 2),
                                   __ATOMIC_RELAXED, __HIP_MEMORY_SCOPE_AGENT);
            // out_hidden stores retire during the poll window
#pragma unroll
            for (int i = 0; i < 4; ++i)
                out_hidden[((size_t)t * B_DIM + (brow0 + i)) * N_DIM + jcol] = a[i];
            if (w == 0) poll_flags(flags, (unsigned)(t + 2), l);
            __builtin_amdgcn_s_barrier();                      // release (no drain)
            asm volatile("" ::: "memory");
        } else {
#pragma unroll
            for (int i = 0; i < 4; ++i)
                out_hidden[((size_t)t * B_DIM + (brow0 + i)) * N_DIM + jcol] = a[i];
        }
    }
}

__global__ void __launch_bounds__(256) geo_kernel(
    const float* __restrict__ hid,
    const float* __restrict__ gW,
    const float* __restrict__ gb,
    const float* __restrict__ rW,
    float* __restrict__ geo,
    float* __restrict__ ro)
{
    int row = blockIdx.x * 4 + (threadIdx.x >> 6);
    int l = threadIdx.x & 63;
    const float* hrow = hid + (size_t)row * N_DIM;
    float a0 = 0.f, a1 = 0.f;
#pragma unroll
    for (int i = 0; i < N_DIM / 64; ++i) {
        int idx = i * 64 + l;
        float th = tanhf(hrow[idx]);
        a0 += th * gW[idx];
        a1 += th * gW[N_DIM + idx];
    }
#pragma unroll
    for (int off = 32; off; off >>= 1) {
        a0 += __shfl_down(a0, off);
        a1 += __shfl_down(a1, off);
    }
    if (l == 0) {
        float g0 = a0 + gb[0];
        float g1 = a1 + gb[1];
        geo[(size_t)row * 2 + 0] = g0;
        geo[(size_t)row * 2 + 1] = g1;
#pragma unroll
        for (int m = 0; m < 6; ++m)
            ro[(size_t)row * 6 + m] = g0 * rW[m * 2] + g1 * rW[m * 2 + 1];
    }
}

extern "C" void kernel_launch(void* const* d_in, const int* in_sizes, int n_in,
                              void* d_out, int out_size, void* d_ws, size_t ws_size,
                              hipStream_t stream) {
    const float* hidden0 = (const float*)d_in[0];
    const float* input   = (const float*)d_in[1];
    const float* lv      = (const float*)d_in[2];
    const float* rv      = (const float*)d_in[3];
    const float* noise   = (const float*)d_in[4];
    const float* gW      = (const float*)d_in[5];
    const float* gb      = (const float*)d_in[6];
    const float* rW      = (const float*)d_in[7];

    float* out_hidden = (float*)d_out;
    float* geo = out_hidden + (size_t)T_DIM * B_DIM * N_DIM;
    float* ro  = geo + (size_t)T_DIM * B_DIM * 2;

    unsigned short* wf    = (unsigned short*)d_ws;                  // 2 MB
    unsigned short* abuf0 = wf + (size_t)64 * 32 * 64 * 8;          // 128 KB
    unsigned short* abuf1 = abuf0 + (size_t)B_DIM * N_DIM;          // 128 KB
    unsigned* flags = (unsigned*)(abuf1 + (size_t)B_DIM * N_DIM);   // 4 KB (padded)

    build_wf<<<2048, 64, 0, stream>>>(lv, rv, noise, wf, flags);

    void* args[] = { (void*)&hidden0, (void*)&input, (void*)&wf,
                     (void*)&out_hidden, (void*)&abuf0, (void*)&abuf1, (void*)&flags };
    hipLaunchCooperativeKernel((const void*)rnn_recurrence, dim3(64), dim3(256),
                               args, 0, stream);

    geo_kernel<<<(T_DIM * B_DIM) / 4, 256, 0, stream>>>(out_hidden, gW, gb, rW, geo, ro);
}

// Round 5
// 2536.314 us; speedup vs baseline: 3.1811x; 1.5317x over previous
//
#include <hip/hip_runtime.h>
#include <hip/hip_bf16.h>

#define N_DIM 1024
#define R_DIM 6
#define B_DIM 64
#define T_DIM 400
#define FLAG_STRIDE 16   // one flag per 64B cacheline

typedef short bf16x8 __attribute__((ext_vector_type(8)));
typedef float f32x4 __attribute__((ext_vector_type(4)));

__device__ inline unsigned short f2bf(float f) {
    unsigned int u = __float_as_uint(f);
    unsigned int r = (u + 0x7fffu + ((u >> 16) & 1u)) >> 16;
    return (unsigned short)r;
}

// Build W in MFMA B-fragment layout, bf16.
// WF[g][s][lane][i] = W[16g + (lane&15)][32s + (lane>>4)*8 + i]
// Block 0 zeroes the 64 per-block flags (deterministic per launch).
__global__ void __launch_bounds__(64) build_wf(
    const float* __restrict__ lv,
    const float* __restrict__ rv,
    const float* __restrict__ noise,
    unsigned short* __restrict__ wf,
    unsigned* __restrict__ flags)
{
    int blk = blockIdx.x;
    int l = threadIdx.x;
    if (blk == 0) flags[l * FLAG_STRIDE] = 0u;
    int g = blk >> 5;
    int s = blk & 31;
    int j = g * 16 + (l & 15);
    int n0 = s * 32 + (l >> 4) * 8;
    unsigned short* dst = wf + ((size_t)blk * 64 + l) * 8;
    float rj[R_DIM];
#pragma unroll
    for (int k = 0; k < R_DIM; ++k) rj[k] = rv[k * N_DIM + j];
#pragma unroll
    for (int i = 0; i < 8; ++i) {
        int n = n0 + i;
        float acc = noise[j * N_DIM + n];
        float dot = 0.f;
#pragma unroll
        for (int k = 0; k < R_DIM; ++k) dot += rj[k] * lv[k * N_DIM + n];
        acc += dot * (1.0f / (float)N_DIM);
        dst[i] = f2bf(acc);
    }
}

// Publish a[4] (rows brow0..brow0+3, col jcol) as packed 2xbf16 u32
// relaxed agent-scope atomic stores (write through to MALL).
__device__ inline void publish_a(unsigned short* dst, const float a[4],
                                 int brow0, int jcol, int l) {
    unsigned* d32 = (unsigned*)dst;
    int j0 = jcol & ~1;
    int odd = l & 1;
#pragma unroll
    for (int i = 0; i < 4; ++i) {
        float other = __shfl_xor(a[i], 1);
        unsigned mine = f2bf(a[i]);
        unsigned oth  = f2bf(other);
        unsigned pk = odd ? (oth | (mine << 16)) : (mine | (oth << 16));
        if ((odd == 0 && i < 2) || (odd == 1 && i >= 2)) {
            int b = brow0 + i;
            __hip_atomic_store(&d32[(b * N_DIM + j0) >> 1], pk,
                               __ATOMIC_RELAXED, __HIP_MEMORY_SCOPE_AGENT);
        }
    }
}

// Wave 0 only: lane l watches block l's flag.
__device__ inline void poll_flags(const unsigned* flags, unsigned target, int l) {
    for (;;) {
        unsigned v = __hip_atomic_load(&flags[l * FLAG_STRIDE],
                                       __ATOMIC_RELAXED, __HIP_MEMORY_SCOPE_AGENT);
        if (__all(v >= target)) break;
        __builtin_amdgcn_s_sleep(1);
    }
}

// Coherent 16B load: bypass L1+L2, read from MALL (coherence point).
#define LOADA(idx, off)                                                        \
    asm volatile("global_load_dwordx4 %0, %1, off offset:" #off " sc0 sc1"     \
                 : "=v"(av[idx]) : "v"(ap) : "memory");

// 64 blocks x 256 threads (cooperative launch for co-residency only).
// Block g owns j-cols [16g,16g+16) for all 64 batches; wave w owns batch
// rows [16w,16w+16). W lives in LDS; a-exchange via MALL-coherent loads;
// ordering via counted vmcnt + raw s_barrier. No fences in the T-loop.
__global__ void __launch_bounds__(256, 1) rnn_recurrence(
    const float* __restrict__ hidden0,
    const float* __restrict__ input,        // [B][T][N]
    const unsigned short* __restrict__ wf,
    float* __restrict__ out_hidden,         // [T][B][N]
    unsigned short* __restrict__ abuf0,
    unsigned short* __restrict__ abuf1,
    unsigned* __restrict__ flags)
{
    const int g = blockIdx.x;
    const int tid = threadIdx.x;
    const int w = tid >> 6;
    const int l = tid & 63;
    const int jcol = g * 16 + (l & 15);
    const int brow0 = w * 16 + (l >> 4) * 4;

    // ---- stage this block's W slice (32 KB) into LDS once ----
    __shared__ unsigned short wlds[16 * 1024];
    {
        const bf16x8* src = reinterpret_cast<const bf16x8*>(wf) + (size_t)g * 2048;
        bf16x8* dstl = reinterpret_cast<bf16x8*>(wlds);
#pragma unroll
        for (int i = 0; i < 8; ++i)
            dstl[tid + i * 256] = src[tid + i * 256];
    }
    __syncthreads();
    const bf16x8* wfrag = reinterpret_cast<const bf16x8*>(wlds);

    // ---- init h-state ----
    float h0v = hidden0[jcol];
    float h[4];
#pragma unroll
    for (int i = 0; i < 4; ++i) h[i] = h0v;

    // prefetch x for t=0 (normal cached loads)
    float x[4];
#pragma unroll
    for (int i = 0; i < 4; ++i)
        x[i] = input[((size_t)(brow0 + i) * T_DIM + 0) * N_DIM + jcol];

    // publish a0
    float a0[4];
#pragma unroll
    for (int i = 0; i < 4; ++i) a0[i] = tanhf(h0v);
    publish_a(abuf0, a0, brow0, jcol, l);
    asm volatile("s_waitcnt vmcnt(0)" ::: "memory");
    __builtin_amdgcn_s_barrier();
    if (tid == 0)
        __hip_atomic_store(&flags[g * FLAG_STRIDE], 1u,
                           __ATOMIC_RELAXED, __HIP_MEMORY_SCOPE_AGENT);
    if (w == 0) poll_flags(flags, 1u, l);
    __builtin_amdgcn_s_barrier();
    asm volatile("" ::: "memory");

    // byte offset of this lane's A-fragment base within the a-buffer
    const int aoff_us = ((w * 16 + (l & 15)) * N_DIM + (l >> 4) * 8);

    for (int t = 0; t < T_DIM; ++t) {
        const unsigned short* acur = (t & 1) ? abuf1 : abuf0;
        unsigned short* anext = (t & 1) ? abuf0 : abuf1;
        const unsigned short* ap = acur + aoff_us;

        // ---- issue 32 coherent a-loads (oldest) ----
        bf16x8 av[32];
        LOADA(0, 0)      LOADA(1, 64)    LOADA(2, 128)   LOADA(3, 192)
        LOADA(4, 256)    LOADA(5, 320)   LOADA(6, 384)   LOADA(7, 448)
        LOADA(8, 512)    LOADA(9, 576)   LOADA(10, 640)  LOADA(11, 704)
        LOADA(12, 768)   LOADA(13, 832)  LOADA(14, 896)  LOADA(15, 960)
        LOADA(16, 1024)  LOADA(17, 1088) LOADA(18, 1152) LOADA(19, 1216)
        LOADA(20, 1280)  LOADA(21, 1344) LOADA(22, 1408) LOADA(23, 1472)
        LOADA(24, 1536)  LOADA(25, 1600) LOADA(26, 1664) LOADA(27, 1728)
        LOADA(28, 1792)  LOADA(29, 1856) LOADA(30, 1920) LOADA(31, 1984)

        // ---- issue 4 x-prefetch loads (youngest; clamped index) ----
        int tn = (t + 1 < T_DIM) ? (t + 1) : t;
        float xn[4];
#pragma unroll
        for (int i = 0; i < 4; ++i)
            xn[i] = input[((size_t)(brow0 + i) * T_DIM + tn) * N_DIM + jcol];

        // all a-loads done (4 youngest = x loads may remain)
        asm volatile("s_waitcnt vmcnt(4)" ::: "memory");
        __builtin_amdgcn_sched_barrier(0);

        f32x4 acc0 = {0.f, 0.f, 0.f, 0.f};
        f32x4 acc1 = {0.f, 0.f, 0.f, 0.f};
        f32x4 acc2 = {0.f, 0.f, 0.f, 0.f};
        f32x4 acc3 = {0.f, 0.f, 0.f, 0.f};
#pragma unroll
        for (int s = 0; s < 32; s += 4) {
            acc0 = __builtin_amdgcn_mfma_f32_16x16x32_bf16(av[s],     wfrag[(s)     * 64 + l], acc0, 0, 0, 0);
            acc1 = __builtin_amdgcn_mfma_f32_16x16x32_bf16(av[s + 1], wfrag[(s + 1) * 64 + l], acc1, 0, 0, 0);
            acc2 = __builtin_amdgcn_mfma_f32_16x16x32_bf16(av[s + 2], wfrag[(s + 2) * 64 + l], acc2, 0, 0, 0);
            acc3 = __builtin_amdgcn_mfma_f32_16x16x32_bf16(av[s + 3], wfrag[(s + 3) * 64 + l], acc3, 0, 0, 0);
        }
        f32x4 acc = (acc0 + acc1) + (acc2 + acc3);

        // x ready
        asm volatile("s_waitcnt vmcnt(0)" ::: "memory");
        __builtin_amdgcn_sched_barrier(0);

        // ---- h update + activation ----
        float a[4];
#pragma unroll
        for (int i = 0; i < 4; ++i) {
            float hn = 0.9f * h[i] + 0.1f * (acc[i] + x[i]);
            h[i] = hn;
            a[i] = tanhf(hn);
        }
#pragma unroll
        for (int i = 0; i < 4; ++i) x[i] = xn[i];

        if (t + 1 < T_DIM) {
            publish_a(anext, a, brow0, jcol, l);
            asm volatile("s_waitcnt vmcnt(0)" ::: "memory");   // publishes at MALL
            __builtin_amdgcn_s_barrier();                      // all waves done
            if (tid == 0)
                __hip_atomic_store(&flags[g * FLAG_STRIDE], (unsigned)(t + 2),
                                   __ATOMIC_RELAXED, __HIP_MEMORY_SCOPE_AGENT);
            // out_hidden stores retire during the poll window
#pragma unroll
            for (int i = 0; i < 4; ++i)
                out_hidden[((size_t)t * B_DIM + (brow0 + i)) * N_DIM + jcol] = a[i];
            if (w == 0) poll_flags(flags, (unsigned)(t + 2), l);
            __builtin_amdgcn_s_barrier();                      // release (no drain)
            asm volatile("" ::: "memory");
        } else {
#pragma unroll
            for (int i = 0; i < 4; ++i)
                out_hidden[((size_t)t * B_DIM + (brow0 + i)) * N_DIM + jcol] = a[i];
        }
    }
}

__global__ void __launch_bounds__(256) geo_kernel(
    const float* __restrict__ hid,
    const float* __restrict__ gW,
    const float* __restrict__ gb,
    const float* __restrict__ rW,
    float* __restrict__ geo,
    float* __restrict__ ro)
{
    int row = blockIdx.x * 4 + (threadIdx.x >> 6);
    int l = threadIdx.x & 63;
    const float* hrow = hid + (size_t)row * N_DIM;
    float a0 = 0.f, a1 = 0.f;
#pragma unroll
    for (int i = 0; i < N_DIM / 64; ++i) {
        int idx = i * 64 + l;
        float th = tanhf(hrow[idx]);
        a0 += th * gW[idx];
        a1 += th * gW[N_DIM + idx];
    }
#pragma unroll
    for (int off = 32; off; off >>= 1) {
        a0 += __shfl_down(a0, off);
        a1 += __shfl_down(a1, off);
    }
    if (l == 0) {
        float g0 = a0 + gb[0];
        float g1 = a1 + gb[1];
        geo[(size_t)row * 2 + 0] = g0;
        geo[(size_t)row * 2 + 1] = g1;
#pragma unroll
        for (int m = 0; m < 6; ++m)
            ro[(size_t)row * 6 + m] = g0 * rW[m * 2] + g1 * rW[m * 2 + 1];
    }
}

extern "C" void kernel_launch(void* const* d_in, const int* in_sizes, int n_in,
                              void* d_out, int out_size, void* d_ws, size_t ws_size,
                              hipStream_t stream) {
    const float* hidden0 = (const float*)d_in[0];
    const float* input   = (const float*)d_in[1];
    const float* lv      = (const float*)d_in[2];
    const float* rv      = (const float*)d_in[3];
    const float* noise   = (const float*)d_in[4];
    const float* gW      = (const float*)d_in[5];
    const float* gb      = (const float*)d_in[6];
    const float* rW      = (const float*)d_in[7];

    float* out_hidden = (float*)d_out;
    float* geo = out_hidden + (size_t)T_DIM * B_DIM * N_DIM;
    float* ro  = geo + (size_t)T_DIM * B_DIM * 2;

    unsigned short* wf    = (unsigned short*)d_ws;                  // 2 MB
    unsigned short* abuf0 = wf + (size_t)64 * 32 * 64 * 8;          // 128 KB
    unsigned short* abuf1 = abuf0 + (size_t)B_DIM * N_DIM;          // 128 KB
    unsigned* flags = (unsigned*)(abuf1 + (size_t)B_DIM * N_DIM);   // 4 KB (padded)

    build_wf<<<2048, 64, 0, stream>>>(lv, rv, noise, wf, flags);

    void* args[] = { (void*)&hidden0, (void*)&input, (void*)&wf,
                     (void*)&out_hidden, (void*)&abuf0, (void*)&abuf1, (void*)&flags };
    hipLaunchCooperativeKernel((const void*)rnn_recurrence, dim3(64), dim3(256),
                               args, 0, stream);

    geo_kernel<<<(T_DIM * B_DIM) / 4, 256, 0, stream>>>(out_hidden, gW, gb, rW, geo, ro);
}

// Round 6
// 2401.593 us; speedup vs baseline: 3.3595x; 1.0561x over previous
//
#include <hip/hip_runtime.h>
#include <hip/hip_bf16.h>

#define N_DIM 1024
#define R_DIM 6
#define B_DIM 64
#define T_DIM 400
#define FLAG_STRIDE 16   // one flag per 64B cacheline

typedef short bf16x8 __attribute__((ext_vector_type(8)));
typedef float f32x4 __attribute__((ext_vector_type(4)));

__device__ inline unsigned short f2bf(float f) {
    unsigned int u = __float_as_uint(f);
    unsigned int r = (u + 0x7fffu + ((u >> 16) & 1u)) >> 16;
    return (unsigned short)r;
}

// Build W in MFMA B-fragment layout, bf16.
// WF[g][s][lane][i] = W[16g + (lane&15)][32s + (lane>>4)*8 + i]
// Block 0 zeroes the 64 per-block flags (deterministic per launch).
__global__ void __launch_bounds__(64) build_wf(
    const float* __restrict__ lv,
    const float* __restrict__ rv,
    const float* __restrict__ noise,
    unsigned short* __restrict__ wf,
    unsigned* __restrict__ flags)
{
    int blk = blockIdx.x;
    int l = threadIdx.x;
    if (blk == 0) flags[l * FLAG_STRIDE] = 0u;
    int g = blk >> 5;
    int s = blk & 31;
    int j = g * 16 + (l & 15);
    int n0 = s * 32 + (l >> 4) * 8;
    unsigned short* dst = wf + ((size_t)blk * 64 + l) * 8;
    float rj[R_DIM];
#pragma unroll
    for (int k = 0; k < R_DIM; ++k) rj[k] = rv[k * N_DIM + j];
#pragma unroll
    for (int i = 0; i < 8; ++i) {
        int n = n0 + i;
        float acc = noise[j * N_DIM + n];
        float dot = 0.f;
#pragma unroll
        for (int k = 0; k < R_DIM; ++k) dot += rj[k] * lv[k * N_DIM + n];
        acc += dot * (1.0f / (float)N_DIM);
        dst[i] = f2bf(acc);
    }
}

// Publish a[4] (rows brow0..brow0+3, col jcol): full-wave, non-atomic,
// write-through (sc0 sc1). Pair transpose: lanes (even,odd) share rows
// brow0..brow0+3 and hold adjacent cols j0, j0+1. Even lane stores rows
// brow0+{0,1}; odd lane stores rows brow0+{2,3}; each store = packed 2xbf16.
__device__ inline void publish_a(unsigned short* dst, const float a[4],
                                 int brow0, int jcol, int l) {
    unsigned* d32 = (unsigned*)dst;
    int odd = l & 1;
    int j0 = jcol & ~1;
#pragma unroll
    for (int k = 0; k < 2; ++k) {
        // even sends a[k+2] (odd needs col j0 of rows brow0+2+k);
        // odd sends a[k] (even needs col j0+1 of rows brow0+k)
        float send = odd ? a[k] : a[k + 2];
        float got = __shfl_xor(send, 1);
        int row = brow0 + (odd ? (k + 2) : k);
        unsigned lo = odd ? f2bf(got)  : f2bf(a[k]);        // col j0
        unsigned hi = odd ? f2bf(a[k + 2]) : f2bf(got);     // col j0+1
        unsigned pk = lo | (hi << 16);
        unsigned* addr = d32 + ((row * N_DIM + j0) >> 1);
        asm volatile("global_store_dword %0, %1, off sc0 sc1"
                     :: "v"(addr), "v"(pk) : "memory");
    }
}

// Wave 0 only: lane l watches block l's flag.
__device__ inline void poll_flags(const unsigned* flags, unsigned target, int l) {
    for (;;) {
        unsigned v = __hip_atomic_load(&flags[l * FLAG_STRIDE],
                                       __ATOMIC_RELAXED, __HIP_MEMORY_SCOPE_AGENT);
        if (__all(v >= target)) break;
        __builtin_amdgcn_s_sleep(1);
    }
}

// Coherent 16B load into register bank slot.
#define LOADA(slot, off)                                                       \
    asm volatile("global_load_dwordx4 %0, %1, off offset:" #off " sc0 sc1"     \
                 : "=v"(av[slot]) : "v"(ap) : "memory");

#define MFMA4(bank, sbase)                                                     \
    acc0 = __builtin_amdgcn_mfma_f32_16x16x32_bf16(av[(bank) * 8 + 0], wfrag[((sbase) + 0) * 64 + l], acc0, 0, 0, 0); \
    acc1 = __builtin_amdgcn_mfma_f32_16x16x32_bf16(av[(bank) * 8 + 1], wfrag[((sbase) + 1) * 64 + l], acc1, 0, 0, 0); \
    acc2 = __builtin_amdgcn_mfma_f32_16x16x32_bf16(av[(bank) * 8 + 2], wfrag[((sbase) + 2) * 64 + l], acc2, 0, 0, 0); \
    acc3 = __builtin_amdgcn_mfma_f32_16x16x32_bf16(av[(bank) * 8 + 3], wfrag[((sbase) + 3) * 64 + l], acc3, 0, 0, 0); \
    acc0 = __builtin_amdgcn_mfma_f32_16x16x32_bf16(av[(bank) * 8 + 4], wfrag[((sbase) + 4) * 64 + l], acc0, 0, 0, 0); \
    acc1 = __builtin_amdgcn_mfma_f32_16x16x32_bf16(av[(bank) * 8 + 5], wfrag[((sbase) + 5) * 64 + l], acc1, 0, 0, 0); \
    acc2 = __builtin_amdgcn_mfma_f32_16x16x32_bf16(av[(bank) * 8 + 6], wfrag[((sbase) + 6) * 64 + l], acc2, 0, 0, 0); \
    acc3 = __builtin_amdgcn_mfma_f32_16x16x32_bf16(av[(bank) * 8 + 7], wfrag[((sbase) + 7) * 64 + l], acc3, 0, 0, 0);

// 64 blocks x 256 threads (cooperative launch for co-residency only).
// Block g owns j-cols [16g,16g+16) for all 64 batches; wave w owns batch
// rows [16w,16w+16). W lives in LDS; a-exchange via MALL-coherent plain
// loads/stores; ordering via counted vmcnt + raw s_barrier. No fences.
__global__ void __launch_bounds__(256, 1) rnn_recurrence(
    const float* __restrict__ hidden0,
    const float* __restrict__ input,        // [B][T][N]
    const unsigned short* __restrict__ wf,
    float* __restrict__ out_hidden,         // [T][B][N]
    unsigned short* __restrict__ abuf0,
    unsigned short* __restrict__ abuf1,
    unsigned* __restrict__ flags)
{
    const int g = blockIdx.x;
    const int tid = threadIdx.x;
    const int w = tid >> 6;
    const int l = tid & 63;
    const int jcol = g * 16 + (l & 15);
    const int brow0 = w * 16 + (l >> 4) * 4;

    // ---- stage this block's W slice (32 KB) into LDS once ----
    __shared__ unsigned short wlds[16 * 1024];
    {
        const bf16x8* src = reinterpret_cast<const bf16x8*>(wf) + (size_t)g * 2048;
        bf16x8* dstl = reinterpret_cast<bf16x8*>(wlds);
#pragma unroll
        for (int i = 0; i < 8; ++i)
            dstl[tid + i * 256] = src[tid + i * 256];
    }
    __syncthreads();
    const bf16x8* wfrag = reinterpret_cast<const bf16x8*>(wlds);

    // ---- init h-state ----
    float h0v = hidden0[jcol];
    float h[4];
#pragma unroll
    for (int i = 0; i < 4; ++i) h[i] = h0v;

    // publish a0
    float a0[4];
#pragma unroll
    for (int i = 0; i < 4; ++i) a0[i] = tanhf(h0v);
    publish_a(abuf0, a0, brow0, jcol, l);
    asm volatile("s_waitcnt vmcnt(0)" ::: "memory");
    __builtin_amdgcn_s_barrier();
    if (tid == 0)
        __hip_atomic_store(&flags[g * FLAG_STRIDE], 1u,
                           __ATOMIC_RELAXED, __HIP_MEMORY_SCOPE_AGENT);
    if (w == 0) poll_flags(flags, 1u, l);
    __builtin_amdgcn_s_barrier();
    asm volatile("" ::: "memory");

    // byte offset of this lane's A-fragment base within the a-buffer
    const int aoff_us = ((w * 16 + (l & 15)) * N_DIM + (l >> 4) * 8);

    for (int t = 0; t < T_DIM; ++t) {
        const unsigned short* acur = (t & 1) ? abuf1 : abuf0;
        unsigned short* anext = (t & 1) ? abuf0 : abuf1;
        const unsigned short* ap = acur + aoff_us;

        // ---- x loads for this step (oldest in queue; consumed after MFMAs) --
        float x[4];
#pragma unroll
        for (int i = 0; i < 4; ++i)
            x[i] = input[((size_t)(brow0 + i) * T_DIM + t) * N_DIM + jcol];

        // ---- pipelined a-loads: 4 groups x 8, two 8-wide register banks ----
        bf16x8 av[16];
        // G0 -> bank0, G1 -> bank1
        LOADA(0, 0)    LOADA(1, 64)   LOADA(2, 128)  LOADA(3, 192)
        LOADA(4, 256)  LOADA(5, 320)  LOADA(6, 384)  LOADA(7, 448)
        LOADA(8, 512)  LOADA(9, 576)  LOADA(10, 640) LOADA(11, 704)
        LOADA(12, 768) LOADA(13, 832) LOADA(14, 896) LOADA(15, 960)

        f32x4 acc0 = {0.f, 0.f, 0.f, 0.f};
        f32x4 acc1 = {0.f, 0.f, 0.f, 0.f};
        f32x4 acc2 = {0.f, 0.f, 0.f, 0.f};
        f32x4 acc3 = {0.f, 0.f, 0.f, 0.f};

        // wait x+G0 (outstanding <= G1's 8)
        asm volatile("s_waitcnt vmcnt(8)" ::: "memory");
        __builtin_amdgcn_sched_barrier(0);
        MFMA4(0, 0)
        // G2 -> bank0 (G0 consumed)
        LOADA(0, 1024) LOADA(1, 1088) LOADA(2, 1152) LOADA(3, 1216)
        LOADA(4, 1280) LOADA(5, 1344) LOADA(6, 1408) LOADA(7, 1472)
        // wait G1 (outstanding <= G2's 8)
        asm volatile("s_waitcnt vmcnt(8)" ::: "memory");
        __builtin_amdgcn_sched_barrier(0);
        MFMA4(1, 8)
        // G3 -> bank1
        LOADA(8, 1536)  LOADA(9, 1600)  LOADA(10, 1664) LOADA(11, 1728)
        LOADA(12, 1792) LOADA(13, 1856) LOADA(14, 1920) LOADA(15, 1984)
        // wait G2
        asm volatile("s_waitcnt vmcnt(8)" ::: "memory");
        __builtin_amdgcn_sched_barrier(0);
        MFMA4(0, 16)
        // wait G3 (and everything else)
        asm volatile("s_waitcnt vmcnt(0)" ::: "memory");
        __builtin_amdgcn_sched_barrier(0);
        MFMA4(1, 24)

        f32x4 acc = (acc0 + acc1) + (acc2 + acc3);

        // ---- h update + activation (x complete: vmcnt(0) above) ----
        float a[4];
#pragma unroll
        for (int i = 0; i < 4; ++i) {
            float hn = 0.9f * h[i] + 0.1f * (acc[i] + x[i]);
            h[i] = hn;
            a[i] = tanhf(hn);
        }

        if (t + 1 < T_DIM) {
            publish_a(anext, a, brow0, jcol, l);
            asm volatile("s_waitcnt vmcnt(0)" ::: "memory");   // publishes at MALL
            __builtin_amdgcn_s_barrier();                      // all waves done
            if (tid == 0)
                __hip_atomic_store(&flags[g * FLAG_STRIDE], (unsigned)(t + 2),
                                   __ATOMIC_RELAXED, __HIP_MEMORY_SCOPE_AGENT);
            // out_hidden stores retire during the poll window
#pragma unroll
            for (int i = 0; i < 4; ++i)
                out_hidden[((size_t)t * B_DIM + (brow0 + i)) * N_DIM + jcol] = a[i];
            if (w == 0) poll_flags(flags, (unsigned)(t + 2), l);
            __builtin_amdgcn_s_barrier();                      // release (no drain)
            asm volatile("" ::: "memory");
        } else {
#pragma unroll
            for (int i = 0; i < 4; ++i)
                out_hidden[((size_t)t * B_DIM + (brow0 + i)) * N_DIM + jcol] = a[i];
        }
    }
}

__global__ void __launch_bounds__(256) geo_kernel(
    const float* __restrict__ hid,
    const float* __restrict__ gW,
    const float* __restrict__ gb,
    const float* __restrict__ rW,
    float* __restrict__ geo,
    float* __restrict__ ro)
{
    int row = blockIdx.x * 4 + (threadIdx.x >> 6);
    int l = threadIdx.x & 63;
    const float* hrow = hid + (size_t)row * N_DIM;
    float a0 = 0.f, a1 = 0.f;
#pragma unroll
    for (int i = 0; i < N_DIM / 64; ++i) {
        int idx = i * 64 + l;
        float th = tanhf(hrow[idx]);
        a0 += th * gW[idx];
        a1 += th * gW[N_DIM + idx];
    }
#pragma unroll
    for (int off = 32; off; off >>= 1) {
        a0 += __shfl_down(a0, off);
        a1 += __shfl_down(a1, off);
    }
    if (l == 0) {
        float g0 = a0 + gb[0];
        float g1 = a1 + gb[1];
        geo[(size_t)row * 2 + 0] = g0;
        geo[(size_t)row * 2 + 1] = g1;
#pragma unroll
        for (int m = 0; m < 6; ++m)
            ro[(size_t)row * 6 + m] = g0 * rW[m * 2] + g1 * rW[m * 2 + 1];
    }
}

extern "C" void kernel_launch(void* const* d_in, const int* in_sizes, int n_in,
                              void* d_out, int out_size, void* d_ws, size_t ws_size,
                              hipStream_t stream) {
    const float* hidden0 = (const float*)d_in[0];
    const float* input   = (const float*)d_in[1];
    const float* lv      = (const float*)d_in[2];
    const float* rv      = (const float*)d_in[3];
    const float* noise   = (const float*)d_in[4];
    const float* gW      = (const float*)d_in[5];
    const float* gb      = (const float*)d_in[6];
    const float* rW      = (const float*)d_in[7];

    float* out_hidden = (float*)d_out;
    float* geo = out_hidden + (size_t)T_DIM * B_DIM * N_DIM;
    float* ro  = geo + (size_t)T_DIM * B_DIM * 2;

    unsigned short* wf    = (unsigned short*)d_ws;                  // 2 MB
    unsigned short* abuf0 = wf + (size_t)64 * 32 * 64 * 8;          // 128 KB
    unsigned short* abuf1 = abuf0 + (size_t)B_DIM * N_DIM;          // 128 KB
    unsigned* flags = (unsigned*)(abuf1 + (size_t)B_DIM * N_DIM);   // 4 KB (padded)

    build_wf<<<2048, 64, 0, stream>>>(lv, rv, noise, wf, flags);

    void* args[] = { (void*)&hidden0, (void*)&input, (void*)&wf,
                     (void*)&out_hidden, (void*)&abuf0, (void*)&abuf1, (void*)&flags };
    hipLaunchCooperativeKernel((const void*)rnn_recurrence, dim3(64), dim3(256),
                               args, 0, stream);

    geo_kernel<<<(T_DIM * B_DIM) / 4, 256, 0, stream>>>(out_hidden, gW, gb, rW, geo, ro);
}